// Round 1
// baseline (377.225 us; speedup 1.0000x reference)
//
#include <hip/hip_runtime.h>
#include <hip/hip_bf16.h>

// Problem constants (from reference)
#define NB 128          // tracklets (b)
#define NS 32           // frames per tracklet (s)
#define DF 256          // feature dim
#define NROW (NB*NS)    // 4096
#define KB 64           // k-tile for pair kernel
#define LDA (KB+4)      // LDS row stride (floats): 68 -> bank=(4u+k)%32, conflict-free with row sets {t,t+8,t+16,t+24}
#define MARGIN 0.3f

// ---------------- Kernel 1: L2 normalize rows + row sumsq ----------------
__global__ __launch_bounds__(64) void norm_kernel(const float* __restrict__ in,
                                                  float* __restrict__ Xn,
                                                  float* __restrict__ sq) {
    const int row = blockIdx.x;      // 0..4095
    const int lane = threadIdx.x;    // 0..63, one float4 each (256 floats/row)
    const float4 v = ((const float4*)(in + (size_t)row * DF))[lane];
    float s = v.x*v.x + v.y*v.y + v.z*v.z + v.w*v.w;
    #pragma unroll
    for (int off = 32; off; off >>= 1) s += __shfl_xor(s, off);
    const float inv = 1.0f / fmaxf(sqrtf(s), 1e-12f);
    float4 o;
    o.x = v.x * inv; o.y = v.y * inv; o.z = v.z * inv; o.w = v.w * inv;
    ((float4*)(Xn + (size_t)row * DF))[lane] = o;
    // sq = sum(Xn*Xn) computed AFTER normalization (mirrors reference)
    float s2 = o.x*o.x + o.y*o.y + o.z*o.z + o.w*o.w;
    #pragma unroll
    for (int off = 32; off; off >>= 1) s2 += __shfl_xor(s2, off);
    if (lane == 0) sq[row] = s2;
}

// ---------------- Kernel 2: per tracklet-pair block value ----------------
// One wave per (i,j). Computes 32x32 distance block, frame-mins both ways,
// k-th largest (k=3 if same identity else 6), combine (max for pos, min for neg).
__global__ __launch_bounds__(64) void pair_kernel(const float* __restrict__ Xn,
                                                  const float* __restrict__ sq,
                                                  const int* __restrict__ tgt,
                                                  float* __restrict__ val) {
    const int j = blockIdx.x;
    const int i = blockIdx.y;
    __shared__ float A[NS][LDA];
    __shared__ float Bm[NS][LDA];
    __shared__ float dblk[NS][NS + 1];
    __shared__ float mins[2][NS];
    __shared__ float kres[2];

    const int tid = threadIdx.x;
    const int tu = tid >> 3;   // 0..7 -> rows {tu, tu+8, tu+16, tu+24}
    const int tt = tid & 7;    // 0..7 -> cols {tt, tt+8, tt+16, tt+24}

    float acc[4][4];
    #pragma unroll
    for (int a = 0; a < 4; a++)
        #pragma unroll
        for (int b = 0; b < 4; b++) acc[a][b] = 0.0f;

    const float* Ap = Xn + (size_t)i * NS * DF;
    const float* Bp = Xn + (size_t)j * NS * DF;

    for (int k0 = 0; k0 < DF; k0 += KB) {
        __syncthreads();
        // stage both panels: 32 rows x (KB/4) float4 each
        #pragma unroll
        for (int idx = tid; idx < NS * (KB / 4); idx += 64) {
            const int r = idx >> 4;        // KB/4 == 16
            const int c4 = (idx & 15) * 4;
            *(float4*)&A[r][c4]  = *(const float4*)(Ap + r * DF + k0 + c4);
            *(float4*)&Bm[r][c4] = *(const float4*)(Bp + r * DF + k0 + c4);
        }
        __syncthreads();
        #pragma unroll
        for (int k = 0; k < KB; k += 4) {
            float4 av[4], bv[4];
            #pragma unroll
            for (int c = 0; c < 4; c++) av[c] = *(const float4*)&A[tu + 8 * c][k];
            #pragma unroll
            for (int c = 0; c < 4; c++) bv[c] = *(const float4*)&Bm[tt + 8 * c][k];
            #pragma unroll
            for (int a = 0; a < 4; a++)
                #pragma unroll
                for (int b = 0; b < 4; b++) {
                    acc[a][b] += av[a].x * bv[b].x + av[a].y * bv[b].y
                               + av[a].z * bv[b].z + av[a].w * bv[b].w;
                }
        }
    }

    // distances into LDS
    #pragma unroll
    for (int a = 0; a < 4; a++) {
        const int u = tu + 8 * a;
        const float squ = sq[i * NS + u];
        #pragma unroll
        for (int b = 0; b < 4; b++) {
            const int t = tt + 8 * b;
            const float sqt = sq[j * NS + t];
            const float d2 = squ + sqt - 2.0f * acc[a][b];
            dblk[u][t] = sqrtf(fmaxf(d2, 1e-12f));
        }
    }
    __syncthreads();

    // lanes 0..31: column mins over u  (dij, indexed by frame t of j)
    // lanes 32..63: row mins over t    (dji, indexed by frame u of i)
    const int half = tid >> 5;
    const int l = tid & 31;
    float m = 1e30f;
    #pragma unroll
    for (int kk = 0; kk < NS; kk++) {
        const float x = half ? dblk[l][kk] : dblk[kk][l];
        m = fminf(m, x);
    }
    mins[half][l] = m;
    __syncthreads();

    const bool pos = (tgt[i] == tgt[j]);
    const int K = pos ? 3 : 6;
    int c = 0, e = 0;
    #pragma unroll
    for (int kk = 0; kk < NS; kk++) {
        const float x = mins[half][kk];
        c += (x > m) ? 1 : 0;
        e += (x == m) ? 1 : 0;
    }
    // K-th largest (0-indexed rank K-1) lives in this lane iff c <= K-1 < c+e
    if (c < K && c + e >= K) kres[half] = m;
    __syncthreads();
    if (tid == 0) {
        const float r = pos ? fmaxf(kres[0], kres[1]) : fminf(kres[0], kres[1]);
        val[i * NB + j] = r;
    }
}

// ---------------- Kernel 3: per-anchor ap/an + mean margin loss ----------------
__global__ __launch_bounds__(128) void reduce_kernel(const float* __restrict__ val,
                                                     const int* __restrict__ tgt,
                                                     float* __restrict__ out) {
    const int i = threadIdx.x;   // 0..127
    const int ti = tgt[i];
    float ap = -1e30f, an = 1e30f;
    for (int j = 0; j < NB; j++) {
        const float v = val[i * NB + j];
        if (tgt[j] == ti) ap = fmaxf(ap, v);
        else              an = fminf(an, v);
    }
    float li = fmaxf(ap - an + MARGIN, 0.0f);
    #pragma unroll
    for (int off = 32; off; off >>= 1) li += __shfl_xor(li, off);
    __shared__ float ws2[2];
    if ((i & 63) == 0) ws2[i >> 6] = li;
    __syncthreads();
    if (i == 0) out[0] = (ws2[0] + ws2[1]) * (1.0f / (float)NB);
}

extern "C" void kernel_launch(void* const* d_in, const int* in_sizes, int n_in,
                              void* d_out, int out_size, void* d_ws, size_t ws_size,
                              hipStream_t stream) {
    const float* in = (const float*)d_in[0];   // (128,32,256) f32
    const int* tgt = (const int*)d_in[1];      // (128,) i32
    float* out = (float*)d_out;                // scalar

    float* Xn = (float*)d_ws;                  // 4096*256 floats
    float* sq = Xn + (size_t)NROW * DF;        // 4096 floats
    float* val = sq + NROW;                    // 128*128 floats

    norm_kernel<<<NROW, 64, 0, stream>>>(in, Xn, sq);
    pair_kernel<<<dim3(NB, NB), 64, 0, stream>>>(Xn, sq, tgt, val);
    reduce_kernel<<<1, 128, 0, stream>>>(val, tgt, out);
}

// Round 2
// 61.749 us; speedup vs baseline: 6.1090x; 6.1090x over previous
//
#include <hip/hip_runtime.h>
#include <hip/hip_bf16.h>

#define NB 128          // tracklets (b)
#define NS 32           // frames per tracklet (s)
#define DF 256          // feature dim
#define NROW (NB*NS)    // 4096
#define KSTEPS (DF/16)  // 16 MFMA k-steps of 16
#define MARGIN 0.3f

typedef short bf16x8 __attribute__((ext_vector_type(8)));
typedef short bf16x4 __attribute__((ext_vector_type(4)));
typedef float f32x16 __attribute__((ext_vector_type(16)));

__device__ __forceinline__ short f2bf(float x) {      // RTNE float->bf16 bits
    unsigned u = __float_as_uint(x);
    u += 0x7fffu + ((u >> 16) & 1u);
    return (short)(u >> 16);
}
__device__ __forceinline__ float bf2f(short b) {
    return __uint_as_float(((unsigned)(unsigned short)b) << 16);
}

// ---------------- Kernel 1: normalize + split into hi/lo bf16 fragment tiles ----------------
// Tile layout (per tracklet): slot = (trk*KSTEPS + ks)*64 + lane, 8 bf16 per slot.
// Fragment semantics: lane l covers frame (l&31), k = ks*16 + (l>>5)*8 + e  -> serves both A and B operands.
__global__ __launch_bounds__(64) void norm_kernel(const float* __restrict__ in,
                                                  short* __restrict__ Xhi,
                                                  short* __restrict__ Xlo,
                                                  float* __restrict__ sq) {
    const int row = blockIdx.x;      // 0..4095
    const int lane = threadIdx.x;    // 0..63, one float4 each
    const float4 v = ((const float4*)(in + (size_t)row * DF))[lane];
    float s = v.x*v.x + v.y*v.y + v.z*v.z + v.w*v.w;
    #pragma unroll
    for (int off = 32; off; off >>= 1) s += __shfl_xor(s, off);
    const float inv = 1.0f / fmaxf(sqrtf(s), 1e-12f);
    const float o[4] = {v.x*inv, v.y*inv, v.z*inv, v.w*inv};

    const int trk = row >> 5, r32 = row & 31;
    const int k4 = lane * 4;
    const int ks = k4 >> 4;
    const int kq = k4 & 15;
    const int tl = ((kq >> 3) << 5) | r32;                    // tile lane
    const size_t off8 = ((size_t)(trk * KSTEPS + ks) * 64 + tl) * 8 + (kq & 7);

    bf16x4 hv, lv;
    #pragma unroll
    for (int c = 0; c < 4; c++) {
        const short hb = f2bf(o[c]);
        hv[c] = hb;
        lv[c] = f2bf(o[c] - bf2f(hb));
    }
    *(bf16x4*)(Xhi + off8) = hv;
    *(bf16x4*)(Xlo + off8) = lv;
    if (lane == 0) sq[row] = s * inv * inv;
}

// ---------------- Kernel 2: MFMA pair-block distances + frame-mins + k-th largest ----------------
// One wave per (i,j); 4 waves/block share i (A-panel L1 reuse).
__global__ __launch_bounds__(256) void pair_kernel(const short* __restrict__ Xhi,
                                                   const short* __restrict__ Xlo,
                                                   const float* __restrict__ sq,
                                                   const int* __restrict__ tgt,
                                                   float* __restrict__ val) {
    const int w = threadIdx.x >> 6;      // wave in block
    const int l = threadIdx.x & 63;
    const int j = blockIdx.x * 4 + w;
    const int i = blockIdx.y;
    const int h = l >> 5;

    const size_t abase = (size_t)i * (KSTEPS * 64) + l;
    const size_t bbase = (size_t)j * (KSTEPS * 64) + l;
    const bf16x8* AhiP = (const bf16x8*)Xhi + abase;
    const bf16x8* AloP = (const bf16x8*)Xlo + abase;
    const bf16x8* BhiP = (const bf16x8*)Xhi + bbase;
    const bf16x8* BloP = (const bf16x8*)Xlo + bbase;

    f32x16 acc;
    #pragma unroll
    for (int r = 0; r < 16; r++) acc[r] = 0.0f;

    #pragma unroll
    for (int ks = 0; ks < KSTEPS; ks++) {
        const bf16x8 ah = AhiP[ks * 64];
        const bf16x8 al = AloP[ks * 64];
        const bf16x8 bh = BhiP[ks * 64];
        const bf16x8 bl = BloP[ks * 64];
        acc = __builtin_amdgcn_mfma_f32_32x32x16_bf16(ah, bh, acc, 0, 0, 0);
        acc = __builtin_amdgcn_mfma_f32_32x32x16_bf16(ah, bl, acc, 0, 0, 0);
        acc = __builtin_amdgcn_mfma_f32_32x32x16_bf16(al, bh, acc, 0, 0, 0);
    }

    // distances: C/D layout col=l&31 (frame t of j), row=(r&3)+8*(r>>2)+4*h (frame u of i)
    const float sqt = sq[j * NS + (l & 31)];
    float d[16];
    #pragma unroll
    for (int r = 0; r < 16; r++) {
        const int row = (r & 3) + 8 * (r >> 2) + 4 * h;
        const float d2 = sq[i * NS + row] + sqt - 2.0f * acc[r];
        d[r] = sqrtf(fmaxf(d2, 1e-12f));
    }

    // dij[t] = min over rows u: in-lane tree + cross-half swap
    float cmin = d[0];
    #pragma unroll
    for (int r = 1; r < 16; r++) cmin = fminf(cmin, d[r]);
    cmin = fminf(cmin, __shfl_xor(cmin, 32));

    // dji[u] = min over cols t: 5-step butterfly within half on all 16 regs
    float rm[16];
    #pragma unroll
    for (int r = 0; r < 16; r++) rm[r] = d[r];
    #pragma unroll
    for (int s = 1; s <= 16; s <<= 1) {
        #pragma unroll
        for (int r = 0; r < 16; r++) rm[r] = fminf(rm[r], __shfl_xor(rm[r], s));
    }

    __shared__ float buf[4][64];
    __shared__ float kres[4][2];
    if (l < 32) buf[w][l] = cmin;
    if ((l & 31) == 0) {
        #pragma unroll
        for (int r = 0; r < 16; r++) buf[w][32 + ((r & 3) + 8 * (r >> 2) + 4 * h)] = rm[r];
    }
    __syncthreads();

    const bool pos = (tgt[i] == tgt[j]);
    const int K = pos ? 3 : 6;
    const float x = buf[w][l];
    const int base = l & 32;
    int c = 0, e = 0;
    #pragma unroll
    for (int t = 0; t < 32; t++) {
        const float y = buf[w][base + t];
        c += (y > x) ? 1 : 0;
        e += (y == x) ? 1 : 0;
    }
    if (c < K && c + e >= K) kres[w][h] = x;   // k-th largest of this half's 32 values
    __syncthreads();
    if (l == 0) val[i * NB + j] = pos ? fmaxf(kres[w][0], kres[w][1])
                                      : fminf(kres[w][0], kres[w][1]);
}

// ---------------- Kernel 3: per-anchor ap/an + mean margin loss ----------------
__global__ __launch_bounds__(128) void reduce_kernel(const float* __restrict__ val,
                                                     const int* __restrict__ tgt,
                                                     float* __restrict__ out) {
    const int i = threadIdx.x;   // 0..127
    const int ti = tgt[i];
    float ap = -1e30f, an = 1e30f;
    for (int j = 0; j < NB; j++) {
        const float v = val[i * NB + j];
        if (tgt[j] == ti) ap = fmaxf(ap, v);
        else              an = fminf(an, v);
    }
    float li = fmaxf(ap - an + MARGIN, 0.0f);
    #pragma unroll
    for (int off = 32; off; off >>= 1) li += __shfl_xor(li, off);
    __shared__ float ws2[2];
    if ((i & 63) == 0) ws2[i >> 6] = li;
    __syncthreads();
    if (i == 0) out[0] = (ws2[0] + ws2[1]) * (1.0f / (float)NB);
}

extern "C" void kernel_launch(void* const* d_in, const int* in_sizes, int n_in,
                              void* d_out, int out_size, void* d_ws, size_t ws_size,
                              hipStream_t stream) {
    const float* in = (const float*)d_in[0];   // (128,32,256) f32
    const int* tgt = (const int*)d_in[1];      // (128,) i32
    float* out = (float*)d_out;                // scalar

    short* Xhi = (short*)d_ws;                         // 4096*256 bf16 (2 MB)
    short* Xlo = Xhi + (size_t)NROW * DF;              // 2 MB
    float* sq  = (float*)(Xlo + (size_t)NROW * DF);    // 16 KB
    float* val = sq + NROW;                            // 64 KB

    norm_kernel<<<NROW, 64, 0, stream>>>(in, Xhi, Xlo, sq);
    pair_kernel<<<dim3(NB / 4, NB), 256, 0, stream>>>(Xhi, Xlo, sq, tgt, val);
    reduce_kernel<<<1, 128, 0, stream>>>(val, tgt, out);
}